// Round 6
// baseline (42.277 us; speedup 1.0000x reference)
//
#include <hip/hip_runtime.h>
#include <math.h>

namespace {

typedef float float2v __attribute__((ext_vector_type(2)));

constexpr int kN = 8;
constexpr int kBatch = 500000;
constexpr int kNPairs = 28;         // 8*7/2
constexpr int kRowsPerBlock = 512;  // 2 rows/thread, packed into float2 lanes
constexpr int kBlocks = (kBatch + kRowsPerBlock - 1) / kRowsPerBlock;  // 977

// Replicates the torch/jax sample_index ordering:
// gaps 2..7 first (each gap g: j=0..N-1-g), then adjacent pairs (j,j+1) at 21..27.
constexpr int pair_index(int a, int b) {
  const int gap = b - a;
  if (gap == 1) return 21 + a;
  int start = 0;
  for (int g = 2; g < gap; ++g) start += kN - g;
  return start + a;
}

// Packed DFS: both rows ride in the two halves of each float2 -> v_pk_add_f32.
// |d| via max(d, -d): the negate folds into a VOP3P neg modifier.
template <int F, int LAST, int SIZE, int NEXT>
__device__ __forceinline__ void dfs(const float2v* x, float2v chain, float2v (&sa)[4]) {
  if constexpr (NEXT < kN) {
    const float2v c2 = chain + x[pair_index(LAST, NEXT)];
    if constexpr (SIZE + 1 >= 3) {
      const float2v d = x[pair_index(F, NEXT)] - c2;
      sa[(F + SIZE + 1) & 3] += __builtin_elementwise_max(d, -d);
    }
    dfs<F, NEXT, SIZE + 1, NEXT + 1>(x, c2, sa);  // extend through NEXT
    dfs<F, LAST, SIZE, NEXT + 1>(x, chain, sa);   // skip NEXT
  }
}

__global__ __launch_bounds__(256, 4) void arc_fused(const float* __restrict__ in,
                                                    float* __restrict__ partial,
                                                    unsigned int* __restrict__ cnt,
                                                    float* __restrict__ out) {
  const int tid = threadIdx.x;
  const int r0 = blockIdx.x * kRowsPerBlock + tid;
  const int r1 = r0 + 256;
  const bool ok0 = r0 < kBatch, ok1 = r1 < kBatch;

  // Load both rows (zeros when out of range), pack into float2 lanes.
  float a0[kNPairs], a1[kNPairs];
#pragma unroll
  for (int k = 0; k < kNPairs; ++k) { a0[k] = 0.0f; a1[k] = 0.0f; }
  if (ok0) {
    const float4* p = reinterpret_cast<const float4*>(in + (size_t)r0 * kNPairs);
#pragma unroll
    for (int j = 0; j < 7; ++j) {
      const float4 t = p[j];
      a0[4 * j] = t.x; a0[4 * j + 1] = t.y; a0[4 * j + 2] = t.z; a0[4 * j + 3] = t.w;
    }
  }
  if (ok1) {
    const float4* p = reinterpret_cast<const float4*>(in + (size_t)r1 * kNPairs);
#pragma unroll
    for (int j = 0; j < 7; ++j) {
      const float4 t = p[j];
      a1[4 * j] = t.x; a1[4 * j + 1] = t.y; a1[4 * j + 2] = t.z; a1[4 * j + 3] = t.w;
    }
  }
  float2v x[kNPairs];
#pragma unroll
  for (int k = 0; k < kNPairs; ++k) x[k] = float2v{a0[k], a1[k]};

  // A-part: adjacent pairs at slots 21..27 (scalar exp, split accumulators)
  float se0a = 0.0f, se0b = 0.0f, se1a = 0.0f, se1b = 0.0f;
#pragma unroll
  for (int k = 21; k < 28; ++k) {
    if (k & 1) { se0a += __expf(-x[k].x); se1a += __expf(-x[k].y); }
    else       { se0b += __expf(-x[k].x); se1b += __expf(-x[k].y); }
  }
  // B-part: 219 packed residuals, 247 packed chain adds
  float2v sa[4] = {float2v{0.f, 0.f}, float2v{0.f, 0.f}, float2v{0.f, 0.f}, float2v{0.f, 0.f}};
  dfs<0, 0, 1, 1>(x, float2v{0.f, 0.f}, sa);
  dfs<1, 1, 1, 2>(x, float2v{0.f, 0.f}, sa);
  dfs<2, 2, 1, 3>(x, float2v{0.f, 0.f}, sa);
  dfs<3, 3, 1, 4>(x, float2v{0.f, 0.f}, sa);
  dfs<4, 4, 1, 5>(x, float2v{0.f, 0.f}, sa);
  dfs<5, 5, 1, 6>(x, float2v{0.f, 0.f}, sa);
  const float2v saT = (sa[0] + sa[1]) + (sa[2] + sa[3]);
  float v0 = (0.5f / 7.0f) * (se0a + se0b) + (0.5f / 219.0f) * saT.x;
  float v1 = (0.5f / 7.0f) * (se1a + se1b) + (0.5f / 219.0f) * saT.y;
  if (!ok0) v0 = 0.0f;
  if (!ok1) v1 = 0.0f;
  float v = v0 + v1;

  // block reduce
#pragma unroll
  for (int off = 32; off > 0; off >>= 1) v += __shfl_down(v, off, 64);
  __shared__ float red[4];
  __shared__ bool last;
  const int lane = tid & 63;
  const int wid = tid >> 6;
  if (lane == 0) red[wid] = v;
  __syncthreads();
  if (tid == 0) {
    partial[blockIdx.x] = red[0] + red[1] + red[2] + red[3];
    __threadfence();  // release: partial visible before counter bump
    last = (atomicAdd(cnt, 1u) == (unsigned int)(kBlocks - 1));
  }
  __syncthreads();

  // Last-arriving block performs the final deterministic reduction.
  if (last) {
    __threadfence();  // acquire: see all other blocks' partials
    double d = 0.0;
    const int n4 = kBlocks >> 2;  // 244
    const float4* p4 = reinterpret_cast<const float4*>(partial);
    for (int i = tid; i < n4; i += 256) {
      const float4 t = p4[i];
      d += (double)t.x + (double)t.y + (double)t.z + (double)t.w;
    }
    for (int i = (n4 << 2) + tid; i < kBlocks; i += 256) d += (double)partial[i];
#pragma unroll
    for (int off = 32; off > 0; off >>= 1) d += __shfl_down(d, off, 64);
    __shared__ double redd[4];
    if (lane == 0) redd[wid] = d;
    __syncthreads();
    if (tid == 0) {
      out[0] = (float)((redd[0] + redd[1] + redd[2] + redd[3]) / (double)kBatch);
    }
  }
}

}  // namespace

extern "C" void kernel_launch(void* const* d_in, const int* in_sizes, int n_in,
                              void* d_out, int out_size, void* d_ws, size_t ws_size,
                              hipStream_t stream) {
  const float* in = (const float*)d_in[0];
  float* out = (float*)d_out;
  float* partial = (float*)d_ws;                                  // 977 floats
  unsigned int* cnt = (unsigned int*)((char*)d_ws + 4096);        // own line
  hipMemsetAsync(cnt, 0, 4, stream);  // re-zero arrival counter每 replay (graph-safe)
  arc_fused<<<kBlocks, 256, 0, stream>>>(in, partial, cnt, out);
}

// Round 7
// 20.537 us; speedup vs baseline: 2.0586x; 2.0586x over previous
//
#include <hip/hip_runtime.h>
#include <math.h>

namespace {

typedef float float2v __attribute__((ext_vector_type(2)));

constexpr int kN = 8;
constexpr int kBatch = 500000;
constexpr int kNPairs = 28;         // 8*7/2
constexpr int kRowsPerBlock = 512;  // 2 rows/thread, packed into float2 lanes
constexpr int kBlocks = (kBatch + kRowsPerBlock - 1) / kRowsPerBlock;  // 977

// Replicates the torch/jax sample_index ordering:
// gaps 2..7 first (each gap g: j=0..N-1-g), then adjacent pairs (j,j+1) at 21..27.
constexpr int pair_index(int a, int b) {
  const int gap = b - a;
  if (gap == 1) return 21 + a;
  int start = 0;
  for (int g = 2; g < gap; ++g) start += kN - g;
  return start + a;
}

// Packed DFS: both rows ride in the two halves of each float2 -> v_pk_add_f32.
// |d| via max(d, -d): the negate folds into a VOP3P neg modifier.
// 247 packed chain adds + 219 packed abs-accumulate for BOTH rows.
template <int F, int LAST, int SIZE, int NEXT>
__device__ __forceinline__ void dfs(const float2v* x, float2v chain, float2v (&sa)[4]) {
  if constexpr (NEXT < kN) {
    const float2v c2 = chain + x[pair_index(LAST, NEXT)];
    if constexpr (SIZE + 1 >= 3) {
      const float2v d = x[pair_index(F, NEXT)] - c2;
      sa[(F + SIZE + 1) & 3] += __builtin_elementwise_max(d, -d);
    }
    dfs<F, NEXT, SIZE + 1, NEXT + 1>(x, c2, sa);  // extend through NEXT
    dfs<F, LAST, SIZE, NEXT + 1>(x, chain, sa);   // skip NEXT
  }
}

// Two-kernel structure (R5-proven): NO device atomics / fences / memset nodes —
// the fused last-block variants (R3, R6) cost +20 us in graph replay.
__global__ __launch_bounds__(256, 4) void arc_main(const float* __restrict__ in,
                                                   float* __restrict__ partial) {
  const int tid = threadIdx.x;
  const int r0 = blockIdx.x * kRowsPerBlock + tid;   // always < kBatch (max 499967)
  const int r1raw = r0 + 256;
  const int r1 = min(r1raw, kBatch - 1);             // clamp: loads always in-bounds

  // Unconditional vector loads for both rows (no predication -> clean codegen).
  const float4* p0 = reinterpret_cast<const float4*>(in + (size_t)r0 * kNPairs);
  const float4* p1 = reinterpret_cast<const float4*>(in + (size_t)r1 * kNPairs);
  float4 t0[7], t1[7];
#pragma unroll
  for (int j = 0; j < 7; ++j) t0[j] = p0[j];
#pragma unroll
  for (int j = 0; j < 7; ++j) t1[j] = p1[j];

  float2v x[kNPairs];
#pragma unroll
  for (int j = 0; j < 7; ++j) {
    x[4 * j + 0] = float2v{t0[j].x, t1[j].x};
    x[4 * j + 1] = float2v{t0[j].y, t1[j].y};
    x[4 * j + 2] = float2v{t0[j].z, t1[j].z};
    x[4 * j + 3] = float2v{t0[j].w, t1[j].w};
  }

  // A-part: adjacent pairs at slots 21..27; scalar v_exp_f32 (transcendental), split accs.
  float se0a = 0.0f, se0b = 0.0f, se1a = 0.0f, se1b = 0.0f;
#pragma unroll
  for (int k = 21; k < 28; ++k) {
    if (k & 1) { se0a += __expf(-x[k].x); se1a += __expf(-x[k].y); }
    else       { se0b += __expf(-x[k].x); se1b += __expf(-x[k].y); }
  }

  // B-part: packed DFS over all 6 chain roots.
  float2v sa[4] = {float2v{0.f, 0.f}, float2v{0.f, 0.f}, float2v{0.f, 0.f}, float2v{0.f, 0.f}};
  dfs<0, 0, 1, 1>(x, float2v{0.f, 0.f}, sa);
  dfs<1, 1, 1, 2>(x, float2v{0.f, 0.f}, sa);
  dfs<2, 2, 1, 3>(x, float2v{0.f, 0.f}, sa);
  dfs<3, 3, 1, 4>(x, float2v{0.f, 0.f}, sa);
  dfs<4, 4, 1, 5>(x, float2v{0.f, 0.f}, sa);
  dfs<5, 5, 1, 6>(x, float2v{0.f, 0.f}, sa);
  const float2v saT = (sa[0] + sa[1]) + (sa[2] + sa[3]);

  const float v0 = (0.5f / 7.0f) * (se0a + se0b) + (0.5f / 219.0f) * saT.x;
  const float v1 = (0.5f / 7.0f) * (se1a + se1b) + (0.5f / 219.0f) * saT.y;
  float v = v0 + ((r1raw < kBatch) ? v1 : 0.0f);   // mask clamped duplicate row

  // wave shuffle reduce + cross-wave LDS reduce
#pragma unroll
  for (int off = 32; off > 0; off >>= 1) v += __shfl_down(v, off, 64);
  __shared__ float red[4];
  const int lane = tid & 63;
  const int wid = tid >> 6;
  if (lane == 0) red[wid] = v;
  __syncthreads();
  if (tid == 0) {
    partial[blockIdx.x] = red[0] + red[1] + red[2] + red[3];
  }
}

__global__ __launch_bounds__(256) void arc_reduce(const float* __restrict__ partial,
                                                  int n, float* __restrict__ out) {
  // n = 977: 244 float4 chunks + 1 scalar tail
  const int n4 = n >> 2;
  double v = 0.0;
  const float4* p4 = reinterpret_cast<const float4*>(partial);
  for (int i = threadIdx.x; i < n4; i += 256) {
    const float4 t = p4[i];
    v += (double)t.x + (double)t.y + (double)t.z + (double)t.w;
  }
  for (int i = (n4 << 2) + threadIdx.x; i < n; i += 256) v += (double)partial[i];
#pragma unroll
  for (int off = 32; off > 0; off >>= 1) v += __shfl_down(v, off, 64);
  __shared__ double red[4];
  const int lane = threadIdx.x & 63;
  const int wid = threadIdx.x >> 6;
  if (lane == 0) red[wid] = v;
  __syncthreads();
  if (threadIdx.x == 0) {
    out[0] = (float)((red[0] + red[1] + red[2] + red[3]) / (double)kBatch);
  }
}

}  // namespace

extern "C" void kernel_launch(void* const* d_in, const int* in_sizes, int n_in,
                              void* d_out, int out_size, void* d_ws, size_t ws_size,
                              hipStream_t stream) {
  const float* in = (const float*)d_in[0];
  float* out = (float*)d_out;
  float* partial = (float*)d_ws;  // kBlocks*4 bytes (~3.9 KB)
  arc_main<<<kBlocks, 256, 0, stream>>>(in, partial);
  arc_reduce<<<1, 256, 0, stream>>>(partial, kBlocks, out);
}